// Round 1
// baseline (480.179 us; speedup 1.0000x reference)
//
#include <hip/hip_runtime.h>
#include <hip/hip_bf16.h>

typedef __hip_bfloat16 bf16;

#define B   128
#define N   2000
#define S   64
#define CAP 128          // max neighbors per row (mean ~65, 8-sigma safe)
#define XROW 1088        // S*17

// ---------------- kernel 1: d[m] = rsqrt(sum(adj[m,:]) + 1) ----------------
__global__ __launch_bounds__(256) void k_rowsum(const float* __restrict__ adj,
                                                float* __restrict__ d) {
    int m = blockIdx.x;
    const float* row = adj + (size_t)m * N;
    float s = 0.f;
    for (int c = threadIdx.x; c < N; c += 256) s += row[c];
    for (int o = 32; o > 0; o >>= 1) s += __shfl_down(s, o);
    __shared__ float red[4];
    int wave = threadIdx.x >> 6;
    if ((threadIdx.x & 63) == 0) red[wave] = s;
    __syncthreads();
    if (threadIdx.x == 0)
        d[m] = rsqrtf(red[0] + red[1] + red[2] + red[3] + 1.0f);
}

// ---------------- kernel 2: CSR of Ahat (ordered ballot compaction) --------
__global__ __launch_bounds__(64) void k_csr(const float* __restrict__ adj,
                                            const float* __restrict__ d,
                                            int* __restrict__ cnt,
                                            int* __restrict__ idx,
                                            float* __restrict__ val) {
    int m = blockIdx.x;
    int lane = threadIdx.x;
    const float* row = adj + (size_t)m * N;
    float dm = d[m];
    int base = 0;
    for (int c0 = 0; c0 < N; c0 += 64) {
        int c = c0 + lane;
        float a = 0.f;
        if (c < N) { a = row[c]; if (c == m) a += 1.0f; }
        bool pred = (a != 0.f);
        unsigned long long mask = __ballot(pred);
        int pos = base + __popcll(mask & ((1ull << lane) - 1ull));
        if (pred && pos < CAP) {
            idx[m * CAP + pos] = c;
            val[m * CAP + pos] = dm * d[c] * a;
        }
        base += (int)__popcll(mask);
    }
    if (lane == 0) cnt[m] = base < CAP ? base : CAP;
}

// ---------------- kernel 3: extract sids / feats / sid_last ----------------
__global__ __launch_bounds__(256) void k_extract(const float* __restrict__ x,
                                                 int* __restrict__ sid,
                                                 int* __restrict__ sid_last,
                                                 float* __restrict__ feats) {
    int b = blockIdx.x, tid = threadIdx.x;
    const float* xb = x + (size_t)b * XROW;
    if (tid < S - 1) sid[b * (S - 1) + tid] = (int)xb[tid * 17 + 15];
    if (tid == S - 1) sid_last[b] = (int)xb[(S - 1) * 17 + 15];
    for (int i = tid; i < (S - 1) * 16; i += 256) {
        int t = i >> 4, f = i & 15;
        feats[(size_t)b * 1008 + i] = xb[t * 17 + (f < 15 ? f : 16)];
    }
}

// ---------------- kernel 4: X1[b,p,:] = relu((Ahat X)[b,p] @ w1 + b1) ------
// one block = (b, 64-node tile); phase1 builds Y=(Ahat X) tile via 63-term
// gather over symmetric adj rows; phase2 K=16 matmul into 256 outputs.
__global__ __launch_bounds__(256) void k_x1(const float* __restrict__ adj,
                                            const float* __restrict__ d,
                                            const int* __restrict__ sid,
                                            const float* __restrict__ feats,
                                            const float* __restrict__ w1,
                                            const float* __restrict__ b1,
                                            bf16* __restrict__ X1) {
    __shared__ float fe[63][16];
    __shared__ float dss[63];
    __shared__ int   sv[64];
    __shared__ float Y[64][17];          // +1 pad: conflict-free writes
    int b = blockIdx.y, p0 = blockIdx.x * 64, tid = threadIdx.x;
    for (int i = tid; i < 63 * 16; i += 256) fe[i >> 4][i & 15] = feats[(size_t)b * 1008 + i];
    if (tid < 63) { int s_ = sid[b * 63 + tid]; sv[tid] = s_; dss[tid] = d[s_]; }
    __syncthreads();

    int pl = tid & 63, fg = tid >> 6;
    int p = p0 + pl;
    if (p < N) {
        float a0 = 0.f, a1 = 0.f, a2 = 0.f, a3 = 0.f;
        int f0 = fg * 4;
        for (int t = 0; t < 63; ++t) {
            int s_ = sv[t];
            float a = adj[(size_t)s_ * N + p];
            if (p == s_) a += 1.0f;
            if (a != 0.f) {
                float w = a * dss[t];
                a0 += w * fe[t][f0 + 0];
                a1 += w * fe[t][f0 + 1];
                a2 += w * fe[t][f0 + 2];
                a3 += w * fe[t][f0 + 3];
            }
        }
        float dp = d[p];
        Y[pl][f0 + 0] = a0 * dp; Y[pl][f0 + 1] = a1 * dp;
        Y[pl][f0 + 2] = a2 * dp; Y[pl][f0 + 3] = a3 * dp;
    }
    __syncthreads();

    float wc[16];
#pragma unroll
    for (int f = 0; f < 16; ++f) wc[f] = w1[f * 256 + tid];
    float bias = b1[tid];
    int pmax = (N - p0 < 64) ? (N - p0) : 64;
    for (int pp = 0; pp < pmax; ++pp) {
        float acc = bias;
#pragma unroll
        for (int f = 0; f < 16; ++f) acc += Y[pp][f] * wc[f];
        acc = acc > 0.f ? acc : 0.f;
        X1[((size_t)b * N + p0 + pp) * 256 + tid] = __float2bfloat16(acc);
    }
}

// ---------------- kernel 5: X2 at one-hop(m_b) -----------------------------
// block = (j, b): n = nbr_j of m_b; agg = sum_k val[n,k]*X1[b,idx[n,k],:];
// X2 = relu(agg @ w2 + b2)
__global__ __launch_bounds__(256) void k_x2(const int* __restrict__ cnt,
                                            const int* __restrict__ idxA,
                                            const float* __restrict__ valA,
                                            const int* __restrict__ sid_last,
                                            const bf16* __restrict__ X1,
                                            const float* __restrict__ w2,
                                            const float* __restrict__ b2,
                                            float* __restrict__ X2) {
    int b = blockIdx.y, j = blockIdx.x, tid = threadIdx.x;
    int m = sid_last[b];
    int cj = cnt[m];
    if (j >= cj) return;
    int n = idxA[m * CAP + j];
    int cn = cnt[n];
    __shared__ int   nidx[CAP];
    __shared__ float nval[CAP];
    __shared__ float aggs[256];
    if (tid < CAP && tid < cn) {
        nidx[tid] = idxA[n * CAP + tid];
        nval[tid] = valA[n * CAP + tid];
    }
    __syncthreads();
    float agg = 0.f;
    for (int k = 0; k < cn; ++k) {
        int p = nidx[k];
        agg += nval[k] * __bfloat162float(X1[((size_t)b * N + p) * 256 + tid]);
    }
    aggs[tid] = agg;
    __syncthreads();
    float acc = b2[tid];
#pragma unroll 4
    for (int f = 0; f < 256; ++f) acc += aggs[f] * w2[f * 256 + tid];
    X2[((size_t)b * CAP + j) * 256 + tid] = acc > 0.f ? acc : 0.f;
}

// ---------------- kernel 6: g[b] = relu((Ahat X2)[b,m_b] @ w3 + b3) --------
__global__ __launch_bounds__(256) void k_g(const int* __restrict__ cnt,
                                           const int* __restrict__ idxA,
                                           const float* __restrict__ valA,
                                           const int* __restrict__ sid_last,
                                           const float* __restrict__ X2,
                                           const float* __restrict__ w3,
                                           const float* __restrict__ b3,
                                           float* __restrict__ g) {
    int b = blockIdx.x, tid = threadIdx.x;
    int m = sid_last[b];
    int cj = cnt[m];
    __shared__ float g1[256];
    float acc = 0.f;
    for (int jj = 0; jj < cj; ++jj)
        acc += valA[m * CAP + jj] * X2[((size_t)b * CAP + jj) * 256 + tid];
    g1[tid] = acc;
    __syncthreads();
    for (int oo = tid; oo < 512; oo += 256) {
        float a2 = b3[oo];
#pragma unroll 4
        for (int f = 0; f < 256; ++f) a2 += g1[f] * w3[f * 512 + oo];
        g[(size_t)b * 512 + oo] = a2 > 0.f ? a2 : 0.f;
    }
}

// ---------------- kernel 7: hp0 = x_last[:, :15] @ w0 + b0 -----------------
__global__ __launch_bounds__(256) void k_fc0(const float* __restrict__ x,
                                             const float* __restrict__ w0,
                                             const float* __restrict__ b0,
                                             float* __restrict__ hp0) {
    int i = blockIdx.x * 256 + threadIdx.x;
    int b = i >> 9, o = i & 511;
    const float* xr = x + (size_t)b * XROW + (S - 1) * 17;
    float acc = b0[o];
#pragma unroll
    for (int f = 0; f < 15; ++f) acc += xr[f] * w0[f * 512 + o];
    hp0[i] = acc;
}

// ---------------- kernel 8/10: batch-norm stats (biased var) ---------------
__global__ __launch_bounds__(256) void k_bnstats(const float* __restrict__ h,
                                                 float* __restrict__ mu,
                                                 float* __restrict__ rstd) {
    int o = blockIdx.x * 256 + threadIdx.x;
    float s = 0.f, s2 = 0.f;
    for (int b = 0; b < B; ++b) { float v = h[b * 512 + o]; s += v; s2 += v * v; }
    float m = s * (1.f / B);
    float var = s2 * (1.f / B) - m * m;
    mu[o] = m;
    rstd[o] = rsqrtf(var + 1e-5f);
}

// ---------------- kernel 9: hp1 = [leaky(bn(hp0)), g] @ w1 + b1 ------------
__global__ __launch_bounds__(256) void k_fc1(const float* __restrict__ hp0,
                                             const float* __restrict__ mu0,
                                             const float* __restrict__ rstd0,
                                             const float* __restrict__ gam,
                                             const float* __restrict__ bet,
                                             const float* __restrict__ gbuf,
                                             const float* __restrict__ w1,
                                             const float* __restrict__ b1,
                                             float* __restrict__ hp1) {
    int b = blockIdx.x, tid = threadIdx.x;
    __shared__ float h0[512], gs[512];
    for (int o = tid; o < 512; o += 256) {
        float v = hp0[b * 512 + o];
        v = gam[o] * (v - mu0[o]) * rstd0[o] + bet[o];
        h0[o] = v >= 0.f ? v : 0.01f * v;
        gs[o] = gbuf[(size_t)b * 512 + o];
    }
    __syncthreads();
    for (int oo = tid; oo < 512; oo += 256) {
        float acc = b1[oo];
#pragma unroll 4
        for (int o = 0; o < 512; ++o) acc += h0[o] * w1[o * 512 + oo];
#pragma unroll 4
        for (int o = 0; o < 512; ++o) acc += gs[o] * w1[(512 + o) * 512 + oo];
        hp1[b * 512 + oo] = acc;
    }
}

// ---------------- kernel 11: out = sigmoid(leaky(bn(hp1)) @ w2 + b2) -------
__global__ __launch_bounds__(64) void k_out(const float* __restrict__ hp1,
                                            const float* __restrict__ mu1,
                                            const float* __restrict__ rstd1,
                                            const float* __restrict__ gam,
                                            const float* __restrict__ bet,
                                            const float* __restrict__ w2,
                                            const float* __restrict__ b2,
                                            float* __restrict__ out) {
    int b = blockIdx.x, lane = threadIdx.x;
    float acc = 0.f;
    for (int o = lane; o < 512; o += 64) {
        float v = hp1[b * 512 + o];
        v = gam[o] * (v - mu1[o]) * rstd1[o] + bet[o];
        v = v >= 0.f ? v : 0.01f * v;
        acc += v * w2[o];
    }
    for (int off = 32; off > 0; off >>= 1) acc += __shfl_down(acc, off);
    if (lane == 0) out[b] = 1.f / (1.f + expf(-(acc + b2[0])));
}

static inline size_t align256(size_t x) { return (x + 255) & ~(size_t)255; }

extern "C" void kernel_launch(void* const* d_in, const int* in_sizes, int n_in,
                              void* d_out, int out_size, void* d_ws, size_t ws_size,
                              hipStream_t stream) {
    const float* x     = (const float*)d_in[0];
    const float* adj   = (const float*)d_in[1];
    const float* w_gc1 = (const float*)d_in[2];
    const float* b_gc1 = (const float*)d_in[3];
    const float* w_gc2 = (const float*)d_in[4];
    const float* b_gc2 = (const float*)d_in[5];
    const float* w_gc3 = (const float*)d_in[6];
    const float* b_gc3 = (const float*)d_in[7];
    const float* w_fc0 = (const float*)d_in[8];
    const float* b_fc0 = (const float*)d_in[9];
    const float* g_fc0 = (const float*)d_in[10];
    const float* be_fc0= (const float*)d_in[11];
    const float* w_fc1 = (const float*)d_in[12];
    const float* b_fc1 = (const float*)d_in[13];
    const float* g_fc1 = (const float*)d_in[14];
    const float* be_fc1= (const float*)d_in[15];
    const float* w_fc2 = (const float*)d_in[16];
    const float* b_fc2 = (const float*)d_in[17];

    char* wsp = (char*)d_ws;
    size_t off = 0;
    auto alloc = [&](size_t bytes) { void* p = wsp + off; off = align256(off + bytes); return p; };
    float* d_deg   = (float*)alloc((size_t)N * 4);
    int*   sid     = (int*)  alloc((size_t)B * 63 * 4);
    int*   sidl    = (int*)  alloc((size_t)B * 4);
    float* feats   = (float*)alloc((size_t)B * 63 * 16 * 4);
    int*   csr_cnt = (int*)  alloc((size_t)N * 4);
    int*   csr_idx = (int*)  alloc((size_t)N * CAP * 4);
    float* csr_val = (float*)alloc((size_t)N * CAP * 4);
    bf16*  X1      = (bf16*) alloc((size_t)B * N * 256 * 2);
    float* X2      = (float*)alloc((size_t)B * CAP * 256 * 4);
    float* gbuf    = (float*)alloc((size_t)B * 512 * 4);
    float* hp0     = (float*)alloc((size_t)B * 512 * 4);
    float* mu0     = (float*)alloc(512 * 4);
    float* rstd0   = (float*)alloc(512 * 4);
    float* hp1     = (float*)alloc((size_t)B * 512 * 4);
    float* mu1     = (float*)alloc(512 * 4);
    float* rstd1   = (float*)alloc(512 * 4);

    k_rowsum <<<N, 256, 0, stream>>>(adj, d_deg);
    k_csr    <<<N, 64, 0, stream>>>(adj, d_deg, csr_cnt, csr_idx, csr_val);
    k_extract<<<B, 256, 0, stream>>>(x, sid, sidl, feats);
    k_x1     <<<dim3(32, B), 256, 0, stream>>>(adj, d_deg, sid, feats, w_gc1, b_gc1, X1);
    k_x2     <<<dim3(CAP, B), 256, 0, stream>>>(csr_cnt, csr_idx, csr_val, sidl, X1, w_gc2, b_gc2, X2);
    k_g      <<<B, 256, 0, stream>>>(csr_cnt, csr_idx, csr_val, sidl, X2, w_gc3, b_gc3, gbuf);
    k_fc0    <<<(B * 512) / 256, 256, 0, stream>>>(x, w_fc0, b_fc0, hp0);
    k_bnstats<<<2, 256, 0, stream>>>(hp0, mu0, rstd0);
    k_fc1    <<<B, 256, 0, stream>>>(hp0, mu0, rstd0, g_fc0, be_fc0, gbuf, w_fc1, b_fc1, hp1);
    k_bnstats<<<2, 256, 0, stream>>>(hp1, mu1, rstd1);
    k_out    <<<B, 64, 0, stream>>>(hp1, mu1, rstd1, g_fc1, be_fc1, w_fc2, b_fc2, (float*)d_out);
}

// Round 2
// 336.344 us; speedup vs baseline: 1.4276x; 1.4276x over previous
//
#include <hip/hip_runtime.h>
#include <hip/hip_bf16.h>

typedef __hip_bfloat16 bf16;

#define B   128
#define N   2000
#define S   64
#define CAP 128          // max neighbors per row (mean ~65, 8-sigma safe)
#define JB  4            // neighbors per block in k_x2
#define XROW 1088        // S*17

// ---------------- kernel 1: d[m] = rsqrt(sum(adj[m,:]) + 1) ----------------
__global__ __launch_bounds__(256) void k_rowsum(const float* __restrict__ adj,
                                                float* __restrict__ d) {
    int m = blockIdx.x;
    const float* row = adj + (size_t)m * N;
    float s = 0.f;
    for (int c = threadIdx.x; c < N; c += 256) s += row[c];
    for (int o = 32; o > 0; o >>= 1) s += __shfl_down(s, o);
    __shared__ float red[4];
    int wave = threadIdx.x >> 6;
    if ((threadIdx.x & 63) == 0) red[wave] = s;
    __syncthreads();
    if (threadIdx.x == 0)
        d[m] = rsqrtf(red[0] + red[1] + red[2] + red[3] + 1.0f);
}

// ---------------- kernel 2: CSR of Ahat (ordered ballot compaction) --------
__global__ __launch_bounds__(64) void k_csr(const float* __restrict__ adj,
                                            const float* __restrict__ d,
                                            int* __restrict__ cnt,
                                            int* __restrict__ idx,
                                            float* __restrict__ val) {
    int m = blockIdx.x;
    int lane = threadIdx.x;
    const float* row = adj + (size_t)m * N;
    float dm = d[m];
    int base = 0;
    for (int c0 = 0; c0 < N; c0 += 64) {
        int c = c0 + lane;
        float a = 0.f;
        if (c < N) { a = row[c]; if (c == m) a += 1.0f; }
        bool pred = (a != 0.f);
        unsigned long long mask = __ballot(pred);
        int pos = base + __popcll(mask & ((1ull << lane) - 1ull));
        if (pred && pos < CAP) {
            idx[m * CAP + pos] = c;
            val[m * CAP + pos] = dm * d[c] * a;
        }
        base += (int)__popcll(mask);
    }
    if (lane == 0) cnt[m] = base < CAP ? base : CAP;
}

// ---------------- kernel 3: extract sids / feats / sid_last ----------------
__global__ __launch_bounds__(256) void k_extract(const float* __restrict__ x,
                                                 int* __restrict__ sid,
                                                 int* __restrict__ sid_last,
                                                 float* __restrict__ feats) {
    int b = blockIdx.x, tid = threadIdx.x;
    const float* xb = x + (size_t)b * XROW;
    if (tid < S - 1) sid[b * (S - 1) + tid] = (int)xb[tid * 17 + 15];
    if (tid == S - 1) sid_last[b] = (int)xb[(S - 1) * 17 + 15];
    for (int i = tid; i < (S - 1) * 16; i += 256) {
        int t = i >> 4, f = i & 15;
        feats[(size_t)b * 1008 + i] = xb[t * 17 + (f < 15 ? f : 16)];
    }
}

// ---------------- kernel 4: X1[b,p,:] = relu((Ahat X)[b,p] @ w1 + b1) ------
__global__ __launch_bounds__(256) void k_x1(const float* __restrict__ adj,
                                            const float* __restrict__ d,
                                            const int* __restrict__ sid,
                                            const float* __restrict__ feats,
                                            const float* __restrict__ w1,
                                            const float* __restrict__ b1,
                                            bf16* __restrict__ X1) {
    __shared__ float fe[63][16];
    __shared__ float dss[63];
    __shared__ int   sv[64];
    __shared__ float Y[64][17];          // +1 pad: conflict-free writes
    int b = blockIdx.y, p0 = blockIdx.x * 64, tid = threadIdx.x;
    for (int i = tid; i < 63 * 16; i += 256) fe[i >> 4][i & 15] = feats[(size_t)b * 1008 + i];
    if (tid < 63) { int s_ = sid[b * 63 + tid]; sv[tid] = s_; dss[tid] = d[s_]; }
    __syncthreads();

    int pl = tid & 63, fg = tid >> 6;
    int p = p0 + pl;
    if (p < N) {
        float a0 = 0.f, a1 = 0.f, a2 = 0.f, a3 = 0.f;
        int f0 = fg * 4;
        for (int t = 0; t < 63; ++t) {
            int s_ = sv[t];
            float a = adj[(size_t)s_ * N + p];
            if (p == s_) a += 1.0f;
            if (a != 0.f) {
                float w = a * dss[t];
                a0 += w * fe[t][f0 + 0];
                a1 += w * fe[t][f0 + 1];
                a2 += w * fe[t][f0 + 2];
                a3 += w * fe[t][f0 + 3];
            }
        }
        float dp = d[p];
        Y[pl][f0 + 0] = a0 * dp; Y[pl][f0 + 1] = a1 * dp;
        Y[pl][f0 + 2] = a2 * dp; Y[pl][f0 + 3] = a3 * dp;
    }
    __syncthreads();

    float wc[16];
#pragma unroll
    for (int f = 0; f < 16; ++f) wc[f] = w1[f * 256 + tid];
    float bias = b1[tid];
    int pmax = (N - p0 < 64) ? (N - p0) : 64;
    for (int pp = 0; pp < pmax; ++pp) {
        float acc = bias;
#pragma unroll
        for (int f = 0; f < 16; ++f) acc += Y[pp][f] * wc[f];
        acc = acc > 0.f ? acc : 0.f;
        X1[((size_t)b * N + p0 + pp) * 256 + tid] = __float2bfloat16(acc);
    }
}

// ---------------- kernel 5: X2 at one-hop(m_b), JB neighbors per block -----
__global__ __launch_bounds__(256) void k_x2(const int* __restrict__ cnt,
                                            const int* __restrict__ idxA,
                                            const float* __restrict__ valA,
                                            const int* __restrict__ sid_last,
                                            const bf16* __restrict__ X1,
                                            const float* __restrict__ w2,
                                            const float* __restrict__ b2,
                                            float* __restrict__ X2) {
    int b = blockIdx.y, j0 = blockIdx.x * JB, tid = threadIdx.x;
    int m = sid_last[b];
    int cj = cnt[m];
    if (j0 >= cj) return;
    int nj = cj - j0; if (nj > JB) nj = JB;

    __shared__ int   nn[JB], ncn[JB];
    __shared__ int   nidx[JB][CAP];
    __shared__ float nval[JB][CAP];
    __shared__ float aggs[JB][256];
    if (tid < JB) {
        int n = idxA[m * CAP + j0 + (tid < nj ? tid : 0)];
        nn[tid] = n;
        ncn[tid] = (tid < nj) ? cnt[n] : 0;
    }
    __syncthreads();
    for (int i = tid; i < JB * CAP; i += 256) {
        int jj = i >> 7, k = i & (CAP - 1);   // CAP==128
        int n = nn[jj];
        nidx[jj][k] = idxA[n * CAP + k];
        nval[jj][k] = valA[n * CAP + k];
    }
    __syncthreads();
#pragma unroll
    for (int jj = 0; jj < JB; ++jj) {
        float agg = 0.f;
        int cn = ncn[jj];
        for (int k = 0; k < cn; ++k)
            agg += nval[jj][k] * __bfloat162float(X1[((size_t)b * N + nidx[jj][k]) * 256 + tid]);
        aggs[jj][tid] = agg;
    }
    __syncthreads();
    float bv = b2[tid];
    float acc0 = bv, acc1 = bv, acc2 = bv, acc3 = bv;
#pragma unroll 4
    for (int f = 0; f < 256; ++f) {
        float w = w2[f * 256 + tid];
        acc0 += aggs[0][f] * w;
        acc1 += aggs[1][f] * w;
        acc2 += aggs[2][f] * w;
        acc3 += aggs[3][f] * w;
    }
    float* o = X2 + ((size_t)b * CAP + j0) * 256 + tid;
    if (0 < nj) o[0 * 256] = acc0 > 0.f ? acc0 : 0.f;
    if (1 < nj) o[1 * 256] = acc1 > 0.f ? acc1 : 0.f;
    if (2 < nj) o[2 * 256] = acc2 > 0.f ? acc2 : 0.f;
    if (3 < nj) o[3 * 256] = acc3 > 0.f ? acc3 : 0.f;
}

// ---------------- kernel 6: g[b] = relu((Ahat X2)[b,m_b] @ w3 + b3) --------
__global__ __launch_bounds__(256) void k_g(const int* __restrict__ cnt,
                                           const int* __restrict__ idxA,
                                           const float* __restrict__ valA,
                                           const int* __restrict__ sid_last,
                                           const float* __restrict__ X2,
                                           const float* __restrict__ w3,
                                           const float* __restrict__ b3,
                                           float* __restrict__ g) {
    int b = blockIdx.x, tid = threadIdx.x;
    int m = sid_last[b];
    int cj = cnt[m];
    __shared__ float g1[256];
    float acc = 0.f;
    for (int jj = 0; jj < cj; ++jj)
        acc += valA[m * CAP + jj] * X2[((size_t)b * CAP + jj) * 256 + tid];
    g1[tid] = acc;
    __syncthreads();
    for (int oo = tid; oo < 512; oo += 256) {
        float a2 = b3[oo];
#pragma unroll 4
        for (int f = 0; f < 256; ++f) a2 += g1[f] * w3[f * 512 + oo];
        g[(size_t)b * 512 + oo] = a2 > 0.f ? a2 : 0.f;
    }
}

// ---------------- kernel 7: hp0 = x_last[:, :15] @ w0 + b0 -----------------
__global__ __launch_bounds__(256) void k_fc0(const float* __restrict__ x,
                                             const float* __restrict__ w0,
                                             const float* __restrict__ b0,
                                             float* __restrict__ hp0) {
    int i = blockIdx.x * 256 + threadIdx.x;
    int b = i >> 9, o = i & 511;
    const float* xr = x + (size_t)b * XROW + (S - 1) * 17;
    float acc = b0[o];
#pragma unroll
    for (int f = 0; f < 15; ++f) acc += xr[f] * w0[f * 512 + o];
    hp0[i] = acc;
}

// ---------------- kernel 8/10: batch-norm stats (biased var) ---------------
__global__ __launch_bounds__(256) void k_bnstats(const float* __restrict__ h,
                                                 float* __restrict__ mu,
                                                 float* __restrict__ rstd) {
    int o = blockIdx.x * 256 + threadIdx.x;
    float s = 0.f, s2 = 0.f;
    for (int b = 0; b < B; ++b) { float v = h[b * 512 + o]; s += v; s2 += v * v; }
    float m = s * (1.f / B);
    float var = s2 * (1.f / B) - m * m;
    mu[o] = m;
    rstd[o] = rsqrtf(var + 1e-5f);
}

// ---------------- kernel 9: hp1 = [leaky(bn(hp0)), g] @ w1 + b1 ------------
// grid (B, 4): 128 outputs per block, 8-way K-split, float4 w loads + LDS reduce
__global__ __launch_bounds__(256) void k_fc1(const float* __restrict__ hp0,
                                             const float* __restrict__ mu0,
                                             const float* __restrict__ rstd0,
                                             const float* __restrict__ gam,
                                             const float* __restrict__ bet,
                                             const float* __restrict__ gbuf,
                                             const float* __restrict__ w1,
                                             const float* __restrict__ b1,
                                             float* __restrict__ hp1) {
    int b = blockIdx.x, ot = blockIdx.y, tid = threadIdx.x;
    __shared__ float h[1024];
    for (int o = tid; o < 512; o += 256) {
        float v = hp0[b * 512 + o];
        v = gam[o] * (v - mu0[o]) * rstd0[o] + bet[o];
        h[o] = v >= 0.f ? v : 0.01f * v;
        h[512 + o] = gbuf[(size_t)b * 512 + o];
    }
    __syncthreads();
    int q  = tid & 31;       // output quad: outputs ot*128 + q*4 .. +3
    int kg = tid >> 5;       // 0..7, K-split group of 128
    const float4* w4 = (const float4*)w1;
    int wq = ot * 32 + q;    // float4 column index (512/4 = 128 per k-row)
    float4 acc = {0.f, 0.f, 0.f, 0.f};
    for (int k = kg * 128; k < kg * 128 + 128; ++k) {
        float hk = h[k];
        float4 w = w4[(size_t)k * 128 + wq];
        acc.x += hk * w.x; acc.y += hk * w.y; acc.z += hk * w.z; acc.w += hk * w.w;
    }
    __shared__ float4 red[8][32];
    red[kg][q] = acc;
    __syncthreads();
    if (tid < 32) {
        float4 s = red[0][tid];
#pragma unroll
        for (int gr = 1; gr < 8; ++gr) {
            float4 r = red[gr][tid];
            s.x += r.x; s.y += r.y; s.z += r.z; s.w += r.w;
        }
        int ob = ot * 128 + tid * 4;
        s.x += b1[ob]; s.y += b1[ob + 1]; s.z += b1[ob + 2]; s.w += b1[ob + 3];
        *(float4*)&hp1[b * 512 + ob] = s;
    }
}

// ---------------- kernel 11: out = sigmoid(leaky(bn(hp1)) @ w2 + b2) -------
__global__ __launch_bounds__(64) void k_out(const float* __restrict__ hp1,
                                            const float* __restrict__ mu1,
                                            const float* __restrict__ rstd1,
                                            const float* __restrict__ gam,
                                            const float* __restrict__ bet,
                                            const float* __restrict__ w2,
                                            const float* __restrict__ b2,
                                            float* __restrict__ out) {
    int b = blockIdx.x, lane = threadIdx.x;
    float acc = 0.f;
    for (int o = lane; o < 512; o += 64) {
        float v = hp1[b * 512 + o];
        v = gam[o] * (v - mu1[o]) * rstd1[o] + bet[o];
        v = v >= 0.f ? v : 0.01f * v;
        acc += v * w2[o];
    }
    for (int off = 32; off > 0; off >>= 1) acc += __shfl_down(acc, off);
    if (lane == 0) out[b] = 1.f / (1.f + expf(-(acc + b2[0])));
}

static inline size_t align256(size_t x) { return (x + 255) & ~(size_t)255; }

extern "C" void kernel_launch(void* const* d_in, const int* in_sizes, int n_in,
                              void* d_out, int out_size, void* d_ws, size_t ws_size,
                              hipStream_t stream) {
    const float* x     = (const float*)d_in[0];
    const float* adj   = (const float*)d_in[1];
    const float* w_gc1 = (const float*)d_in[2];
    const float* b_gc1 = (const float*)d_in[3];
    const float* w_gc2 = (const float*)d_in[4];
    const float* b_gc2 = (const float*)d_in[5];
    const float* w_gc3 = (const float*)d_in[6];
    const float* b_gc3 = (const float*)d_in[7];
    const float* w_fc0 = (const float*)d_in[8];
    const float* b_fc0 = (const float*)d_in[9];
    const float* g_fc0 = (const float*)d_in[10];
    const float* be_fc0= (const float*)d_in[11];
    const float* w_fc1 = (const float*)d_in[12];
    const float* b_fc1 = (const float*)d_in[13];
    const float* g_fc1 = (const float*)d_in[14];
    const float* be_fc1= (const float*)d_in[15];
    const float* w_fc2 = (const float*)d_in[16];
    const float* b_fc2 = (const float*)d_in[17];

    char* wsp = (char*)d_ws;
    size_t off = 0;
    auto alloc = [&](size_t bytes) { void* p = wsp + off; off = align256(off + bytes); return p; };
    float* d_deg   = (float*)alloc((size_t)N * 4);
    int*   sid     = (int*)  alloc((size_t)B * 63 * 4);
    int*   sidl    = (int*)  alloc((size_t)B * 4);
    float* feats   = (float*)alloc((size_t)B * 63 * 16 * 4);
    int*   csr_cnt = (int*)  alloc((size_t)N * 4);
    int*   csr_idx = (int*)  alloc((size_t)N * CAP * 4);
    float* csr_val = (float*)alloc((size_t)N * CAP * 4);
    bf16*  X1      = (bf16*) alloc((size_t)B * N * 256 * 2);
    float* X2      = (float*)alloc((size_t)B * CAP * 256 * 4);
    float* gbuf    = (float*)alloc((size_t)B * 512 * 4);
    float* hp0     = (float*)alloc((size_t)B * 512 * 4);
    float* mu0     = (float*)alloc(512 * 4);
    float* rstd0   = (float*)alloc(512 * 4);
    float* hp1     = (float*)alloc((size_t)B * 512 * 4);
    float* mu1     = (float*)alloc(512 * 4);
    float* rstd1   = (float*)alloc(512 * 4);

    k_rowsum <<<N, 256, 0, stream>>>(adj, d_deg);
    k_csr    <<<N, 64, 0, stream>>>(adj, d_deg, csr_cnt, csr_idx, csr_val);
    k_extract<<<B, 256, 0, stream>>>(x, sid, sidl, feats);
    k_x1     <<<dim3(32, B), 256, 0, stream>>>(adj, d_deg, sid, feats, w_gc1, b_gc1, X1);
    k_x2     <<<dim3(CAP / JB, B), 256, 0, stream>>>(csr_cnt, csr_idx, csr_val, sidl, X1, w_gc2, b_gc2, X2);
    k_g      <<<B, 256, 0, stream>>>(csr_cnt, csr_idx, csr_val, sidl, X2, w_gc3, b_gc3, gbuf);
    k_fc0    <<<(B * 512) / 256, 256, 0, stream>>>(x, w_fc0, b_fc0, hp0);
    k_bnstats<<<2, 256, 0, stream>>>(hp0, mu0, rstd0);
    k_fc1    <<<dim3(B, 4), 256, 0, stream>>>(hp0, mu0, rstd0, g_fc0, be_fc0, gbuf, w_fc1, b_fc1, hp1);
    k_bnstats<<<2, 256, 0, stream>>>(hp1, mu1, rstd1);
    k_out    <<<B, 64, 0, stream>>>(hp1, mu1, rstd1, g_fc1, be_fc1, w_fc2, b_fc2, (float*)d_out);
}

// Round 3
// 297.018 us; speedup vs baseline: 1.6167x; 1.1324x over previous
//
#include <hip/hip_runtime.h>
#include <hip/hip_bf16.h>

typedef __hip_bfloat16 bf16;
typedef short s8v __attribute__((ext_vector_type(8)));
typedef float f4v __attribute__((ext_vector_type(4)));

#define B   128
#define N   2000
#define S   64
#define CAP 128          // max neighbors per row (mean ~65, 8-sigma safe)
#define JB  4            // neighbors per block in k_x2
#define XROW 1088        // S*17

__device__ inline ushort bfb(float v) {
    union { __hip_bfloat16 h; ushort u; } c; c.h = __float2bfloat16(v); return c.u;
}

// ---------------- kernel 1: d[m] = rsqrt(sum(adj[m,:]) + 1) ----------------
__global__ __launch_bounds__(256) void k_rowsum(const float* __restrict__ adj,
                                                float* __restrict__ d) {
    int m = blockIdx.x;
    const float* row = adj + (size_t)m * N;
    float s = 0.f;
    for (int c = threadIdx.x; c < N; c += 256) s += row[c];
    for (int o = 32; o > 0; o >>= 1) s += __shfl_down(s, o);
    __shared__ float red[4];
    int wave = threadIdx.x >> 6;
    if ((threadIdx.x & 63) == 0) red[wave] = s;
    __syncthreads();
    if (threadIdx.x == 0)
        d[m] = rsqrtf(red[0] + red[1] + red[2] + red[3] + 1.0f);
}

// ---------------- kernel 2: CSR of Ahat (ordered ballot compaction) --------
__global__ __launch_bounds__(64) void k_csr(const float* __restrict__ adj,
                                            const float* __restrict__ d,
                                            int* __restrict__ cnt,
                                            int* __restrict__ idx,
                                            float* __restrict__ val) {
    int m = blockIdx.x;
    int lane = threadIdx.x;
    const float* row = adj + (size_t)m * N;
    float dm = d[m];
    int base = 0;
    for (int c0 = 0; c0 < N; c0 += 64) {
        int c = c0 + lane;
        float a = 0.f;
        if (c < N) { a = row[c]; if (c == m) a += 1.0f; }
        bool pred = (a != 0.f);
        unsigned long long mask = __ballot(pred);
        int pos = base + __popcll(mask & ((1ull << lane) - 1ull));
        if (pred && pos < CAP) {
            idx[m * CAP + pos] = c;
            val[m * CAP + pos] = dm * d[c] * a;
        }
        base += (int)__popcll(mask);
    }
    if (lane == 0) cnt[m] = base < CAP ? base : CAP;
}

// ---------------- kernel 3: extract sids / sid_last / dss-premult feats ----
__global__ __launch_bounds__(256) void k_extract(const float* __restrict__ x,
                                                 const float* __restrict__ d,
                                                 int* __restrict__ sid,
                                                 int* __restrict__ sid_last,
                                                 float* __restrict__ fes) {
    int b = blockIdx.x, tid = threadIdx.x;
    const float* xb = x + (size_t)b * XROW;
    __shared__ float dss_sh[63];
    if (tid < S - 1) {
        int s_ = (int)xb[tid * 17 + 15];
        sid[b * (S - 1) + tid] = s_;
        dss_sh[tid] = d[s_];
    }
    if (tid == S - 1) sid_last[b] = (int)xb[(S - 1) * 17 + 15];
    __syncthreads();
    for (int i = tid; i < (S - 1) * 16; i += 256) {
        int t = i >> 4, f = i & 15;
        fes[(size_t)b * 1008 + i] = dss_sh[t] * xb[t * 17 + (f < 15 ? f : 16)];
    }
}

// ---------------- kernel 3b: pack W1^T MFMA fragments (bf16, K-pad to 32) --
// entry e = ct*64 + lane: 8 bf16 of W[(lane>>4)*8 + j][ct*16 + (lane&15)], 0 for k>=16
__global__ __launch_bounds__(256) void k_wfrag(const float* __restrict__ w1,
                                               uint4* __restrict__ wf) {
    int e = blockIdx.x * 256 + threadIdx.x;       // 0..1023
    int ct = e >> 6, l = e & 63;
    int kg = l >> 4, ch = ct * 16 + (l & 15);
    ushort h[8];
#pragma unroll
    for (int j = 0; j < 8; ++j) {
        int f = kg * 8 + j;
        h[j] = (f < 16) ? bfb(w1[f * 256 + ch]) : (ushort)0;
    }
    uint4 r;
    r.x = h[0] | ((uint)h[1] << 16);
    r.y = h[2] | ((uint)h[3] << 16);
    r.z = h[4] | ((uint)h[5] << 16);
    r.w = h[6] | ((uint)h[7] << 16);
    wf[e] = r;
}

// ---------------- kernel 4: X1[b,p,:] = relu((Ahat X)[b,p] @ w1 + b1) ------
// phase 1: 63-term gather with scalar-pipe feat reads -> Y (bf16, LDS)
// phase 2: mfma_f32_16x16x32_bf16, D = W^T * Y^T -> packed 8B stores
__global__ __launch_bounds__(256) void k_x1(const float* __restrict__ adj,
                                            const float* __restrict__ d,
                                            const int* __restrict__ sid,
                                            const float* __restrict__ fes,
                                            const uint4* __restrict__ wfrag,
                                            const float* __restrict__ b1,
                                            bf16* __restrict__ X1) {
    __shared__ ushort Ylds[64][32];
    __shared__ float b1s[256];
    int b = blockIdx.y, p0 = blockIdx.x * 64, tid = threadIdx.x;
    b1s[tid] = b1[tid];

    int pl = tid & 63;
    int fgu = __builtin_amdgcn_readfirstlane(tid >> 6);   // wave-uniform -> SGPR
    int f0 = fgu * 4;
    int p = p0 + pl;
    const float* fes_b = fes + (size_t)b * 1008 + f0;     // uniform base
    const int* sid_b = sid + b * 63;
    float a0 = 0.f, a1 = 0.f, a2 = 0.f, a3 = 0.f;
    if (p < N) {
        for (int t = 0; t < 63; ++t) {
            int s_ = sid_b[t];                             // uniform -> s_load
            float a = adj[(size_t)s_ * N + p];
            if (p == s_) a += 1.0f;
            const float* fr = fes_b + t * 16;              // uniform -> s_load
            a0 += a * fr[0]; a1 += a * fr[1];
            a2 += a * fr[2]; a3 += a * fr[3];
        }
    }
    float dp = (p < N) ? d[p] : 0.f;
    a0 *= dp; a1 *= dp; a2 *= dp; a3 *= dp;
    uint lo = bfb(a0) | ((uint)bfb(a1) << 16);
    uint hi = bfb(a2) | ((uint)bfb(a3) << 16);
    *(uint2*)&Ylds[pl][f0] = make_uint2(lo, hi);
    *(uint2*)&Ylds[pl][16 + f0] = make_uint2(0u, 0u);      // K-pad zeros
    __syncthreads();

    // ---- phase 2 ----
    int l = tid & 63, wv = tid >> 6;
    int lm = l & 15, lg = l >> 4;
    s8v yf = *(const s8v*)&Ylds[wv * 16 + lm][lg * 8];     // B = Y^T frag
    f4v acc[16];
#pragma unroll
    for (int ct = 0; ct < 16; ++ct) acc[ct] = (f4v){0.f, 0.f, 0.f, 0.f};
#pragma unroll
    for (int ct = 0; ct < 16; ++ct) {
        s8v wfv = *(const s8v*)&wfrag[ct * 64 + l];        // A = W^T frag
        acc[ct] = __builtin_amdgcn_mfma_f32_16x16x32_bf16(wfv, yf, acc[ct], 0, 0, 0);
    }
    int pp = p0 + wv * 16 + lm;
    if (pp < N) {
        uint2* dst = (uint2*)X1 + ((size_t)b * N + pp) * 64;
#pragma unroll
        for (int ct = 0; ct < 16; ++ct) {
            float4 bz = *(float4*)&b1s[ct * 16 + lg * 4];
            float v0 = acc[ct][0] + bz.x; v0 = v0 > 0.f ? v0 : 0.f;
            float v1 = acc[ct][1] + bz.y; v1 = v1 > 0.f ? v1 : 0.f;
            float v2 = acc[ct][2] + bz.z; v2 = v2 > 0.f ? v2 : 0.f;
            float v3 = acc[ct][3] + bz.w; v3 = v3 > 0.f ? v3 : 0.f;
            uint2 pk;
            pk.x = bfb(v0) | ((uint)bfb(v1) << 16);
            pk.y = bfb(v2) | ((uint)bfb(v3) << 16);
            dst[ct * 4 + lg] = pk;
        }
    }
}

// ---------------- kernel 5: X2 at one-hop(m_b), JB neighbors per block -----
__global__ __launch_bounds__(256) void k_x2(const int* __restrict__ cnt,
                                            const int* __restrict__ idxA,
                                            const float* __restrict__ valA,
                                            const int* __restrict__ sid_last,
                                            const bf16* __restrict__ X1,
                                            const float* __restrict__ w2,
                                            const float* __restrict__ b2,
                                            float* __restrict__ X2) {
    int b = blockIdx.y, j0 = blockIdx.x * JB, tid = threadIdx.x;
    int m = sid_last[b];
    int cj = cnt[m];
    if (j0 >= cj) return;
    int nj = cj - j0; if (nj > JB) nj = JB;

    __shared__ int   nn[JB], ncn[JB];
    __shared__ int   nidx[JB][CAP];
    __shared__ float nval[JB][CAP];
    __shared__ float aggs[JB][256];
    if (tid < JB) {
        int n = idxA[m * CAP + j0 + (tid < nj ? tid : 0)];
        nn[tid] = n;
        ncn[tid] = (tid < nj) ? cnt[n] : 0;
    }
    __syncthreads();
    for (int i = tid; i < JB * CAP; i += 256) {
        int jj = i >> 7, k = i & (CAP - 1);   // CAP==128
        int n = nn[jj];
        nidx[jj][k] = idxA[n * CAP + k];
        nval[jj][k] = valA[n * CAP + k];
    }
    __syncthreads();
#pragma unroll
    for (int jj = 0; jj < JB; ++jj) {
        float agg = 0.f;
        int cn = ncn[jj];
        for (int k = 0; k < cn; ++k)
            agg += nval[jj][k] * __bfloat162float(X1[((size_t)b * N + nidx[jj][k]) * 256 + tid]);
        aggs[jj][tid] = agg;
    }
    __syncthreads();
    float bv = b2[tid];
    float acc0 = bv, acc1 = bv, acc2 = bv, acc3 = bv;
#pragma unroll 4
    for (int f = 0; f < 256; ++f) {
        float w = w2[f * 256 + tid];
        acc0 += aggs[0][f] * w;
        acc1 += aggs[1][f] * w;
        acc2 += aggs[2][f] * w;
        acc3 += aggs[3][f] * w;
    }
    float* o = X2 + ((size_t)b * CAP + j0) * 256 + tid;
    if (0 < nj) o[0 * 256] = acc0 > 0.f ? acc0 : 0.f;
    if (1 < nj) o[1 * 256] = acc1 > 0.f ? acc1 : 0.f;
    if (2 < nj) o[2 * 256] = acc2 > 0.f ? acc2 : 0.f;
    if (3 < nj) o[3 * 256] = acc3 > 0.f ? acc3 : 0.f;
}

// ---------------- kernel 6: g[b] = relu((Ahat X2)[b,m_b] @ w3 + b3) --------
__global__ __launch_bounds__(256) void k_g(const int* __restrict__ cnt,
                                           const int* __restrict__ idxA,
                                           const float* __restrict__ valA,
                                           const int* __restrict__ sid_last,
                                           const float* __restrict__ X2,
                                           const float* __restrict__ w3,
                                           const float* __restrict__ b3,
                                           float* __restrict__ g) {
    int b = blockIdx.x, tid = threadIdx.x;
    int m = sid_last[b];
    int cj = cnt[m];
    __shared__ float g1[256];
    float acc = 0.f;
    for (int jj = 0; jj < cj; ++jj)
        acc += valA[m * CAP + jj] * X2[((size_t)b * CAP + jj) * 256 + tid];
    g1[tid] = acc;
    __syncthreads();
    for (int oo = tid; oo < 512; oo += 256) {
        float a2 = b3[oo];
#pragma unroll 4
        for (int f = 0; f < 256; ++f) a2 += g1[f] * w3[f * 512 + oo];
        g[(size_t)b * 512 + oo] = a2 > 0.f ? a2 : 0.f;
    }
}

// ---------------- kernel 7: hp0 = x_last[:, :15] @ w0 + b0 -----------------
__global__ __launch_bounds__(256) void k_fc0(const float* __restrict__ x,
                                             const float* __restrict__ w0,
                                             const float* __restrict__ b0,
                                             float* __restrict__ hp0) {
    int i = blockIdx.x * 256 + threadIdx.x;
    int b = i >> 9, o = i & 511;
    const float* xr = x + (size_t)b * XROW + (S - 1) * 17;
    float acc = b0[o];
#pragma unroll
    for (int f = 0; f < 15; ++f) acc += xr[f] * w0[f * 512 + o];
    hp0[i] = acc;
}

// ---------------- kernel 8/10: batch-norm stats (biased var) ---------------
__global__ __launch_bounds__(256) void k_bnstats(const float* __restrict__ h,
                                                 float* __restrict__ mu,
                                                 float* __restrict__ rstd) {
    int o = blockIdx.x * 256 + threadIdx.x;
    float s = 0.f, s2 = 0.f;
    for (int b = 0; b < B; ++b) { float v = h[b * 512 + o]; s += v; s2 += v * v; }
    float m = s * (1.f / B);
    float var = s2 * (1.f / B) - m * m;
    mu[o] = m;
    rstd[o] = rsqrtf(var + 1e-5f);
}

// ---------------- kernel 9: hp1 = [leaky(bn(hp0)), g] @ w1 + b1 ------------
__global__ __launch_bounds__(256) void k_fc1(const float* __restrict__ hp0,
                                             const float* __restrict__ mu0,
                                             const float* __restrict__ rstd0,
                                             const float* __restrict__ gam,
                                             const float* __restrict__ bet,
                                             const float* __restrict__ gbuf,
                                             const float* __restrict__ w1,
                                             const float* __restrict__ b1,
                                             float* __restrict__ hp1) {
    int b = blockIdx.x, ot = blockIdx.y, tid = threadIdx.x;
    __shared__ float h[1024];
    for (int o = tid; o < 512; o += 256) {
        float v = hp0[b * 512 + o];
        v = gam[o] * (v - mu0[o]) * rstd0[o] + bet[o];
        h[o] = v >= 0.f ? v : 0.01f * v;
        h[512 + o] = gbuf[(size_t)b * 512 + o];
    }
    __syncthreads();
    int q  = tid & 31;
    int kg = tid >> 5;
    const float4* w4 = (const float4*)w1;
    int wq = ot * 32 + q;
    float4 acc = {0.f, 0.f, 0.f, 0.f};
    for (int k = kg * 128; k < kg * 128 + 128; ++k) {
        float hk = h[k];
        float4 w = w4[(size_t)k * 128 + wq];
        acc.x += hk * w.x; acc.y += hk * w.y; acc.z += hk * w.z; acc.w += hk * w.w;
    }
    __shared__ float4 red[8][32];
    red[kg][q] = acc;
    __syncthreads();
    if (tid < 32) {
        float4 s = red[0][tid];
#pragma unroll
        for (int gr = 1; gr < 8; ++gr) {
            float4 r = red[gr][tid];
            s.x += r.x; s.y += r.y; s.z += r.z; s.w += r.w;
        }
        int ob = ot * 128 + tid * 4;
        s.x += b1[ob]; s.y += b1[ob + 1]; s.z += b1[ob + 2]; s.w += b1[ob + 3];
        *(float4*)&hp1[b * 512 + ob] = s;
    }
}

// ---------------- kernel 11: out = sigmoid(leaky(bn(hp1)) @ w2 + b2) -------
__global__ __launch_bounds__(64) void k_out(const float* __restrict__ hp1,
                                            const float* __restrict__ mu1,
                                            const float* __restrict__ rstd1,
                                            const float* __restrict__ gam,
                                            const float* __restrict__ bet,
                                            const float* __restrict__ w2,
                                            const float* __restrict__ b2,
                                            float* __restrict__ out) {
    int b = blockIdx.x, lane = threadIdx.x;
    float acc = 0.f;
    for (int o = lane; o < 512; o += 64) {
        float v = hp1[b * 512 + o];
        v = gam[o] * (v - mu1[o]) * rstd1[o] + bet[o];
        v = v >= 0.f ? v : 0.01f * v;
        acc += v * w2[o];
    }
    for (int off = 32; off > 0; off >>= 1) acc += __shfl_down(acc, off);
    if (lane == 0) out[b] = 1.f / (1.f + expf(-(acc + b2[0])));
}

static inline size_t align256(size_t x) { return (x + 255) & ~(size_t)255; }

extern "C" void kernel_launch(void* const* d_in, const int* in_sizes, int n_in,
                              void* d_out, int out_size, void* d_ws, size_t ws_size,
                              hipStream_t stream) {
    const float* x     = (const float*)d_in[0];
    const float* adj   = (const float*)d_in[1];
    const float* w_gc1 = (const float*)d_in[2];
    const float* b_gc1 = (const float*)d_in[3];
    const float* w_gc2 = (const float*)d_in[4];
    const float* b_gc2 = (const float*)d_in[5];
    const float* w_gc3 = (const float*)d_in[6];
    const float* b_gc3 = (const float*)d_in[7];
    const float* w_fc0 = (const float*)d_in[8];
    const float* b_fc0 = (const float*)d_in[9];
    const float* g_fc0 = (const float*)d_in[10];
    const float* be_fc0= (const float*)d_in[11];
    const float* w_fc1 = (const float*)d_in[12];
    const float* b_fc1 = (const float*)d_in[13];
    const float* g_fc1 = (const float*)d_in[14];
    const float* be_fc1= (const float*)d_in[15];
    const float* w_fc2 = (const float*)d_in[16];
    const float* b_fc2 = (const float*)d_in[17];

    char* wsp = (char*)d_ws;
    size_t off = 0;
    auto alloc = [&](size_t bytes) { void* p = wsp + off; off = align256(off + bytes); return p; };
    float* d_deg   = (float*)alloc((size_t)N * 4);
    int*   sid     = (int*)  alloc((size_t)B * 63 * 4);
    int*   sidl    = (int*)  alloc((size_t)B * 4);
    float* fes     = (float*)alloc((size_t)B * 63 * 16 * 4);
    uint4* wfrag   = (uint4*)alloc((size_t)1024 * 16);
    int*   csr_cnt = (int*)  alloc((size_t)N * 4);
    int*   csr_idx = (int*)  alloc((size_t)N * CAP * 4);
    float* csr_val = (float*)alloc((size_t)N * CAP * 4);
    bf16*  X1      = (bf16*) alloc((size_t)B * N * 256 * 2);
    float* X2      = (float*)alloc((size_t)B * CAP * 256 * 4);
    float* gbuf    = (float*)alloc((size_t)B * 512 * 4);
    float* hp0     = (float*)alloc((size_t)B * 512 * 4);
    float* mu0     = (float*)alloc(512 * 4);
    float* rstd0   = (float*)alloc(512 * 4);
    float* hp1     = (float*)alloc((size_t)B * 512 * 4);
    float* mu1     = (float*)alloc(512 * 4);
    float* rstd1   = (float*)alloc(512 * 4);

    k_rowsum <<<N, 256, 0, stream>>>(adj, d_deg);
    k_csr    <<<N, 64, 0, stream>>>(adj, d_deg, csr_cnt, csr_idx, csr_val);
    k_extract<<<B, 256, 0, stream>>>(x, d_deg, sid, sidl, fes);
    k_wfrag  <<<4, 256, 0, stream>>>(w_gc1, wfrag);
    k_x1     <<<dim3(32, B), 256, 0, stream>>>(adj, d_deg, sid, fes, wfrag, b_gc1, X1);
    k_x2     <<<dim3(CAP / JB, B), 256, 0, stream>>>(csr_cnt, csr_idx, csr_val, sidl, X1, w_gc2, b_gc2, X2);
    k_g      <<<B, 256, 0, stream>>>(csr_cnt, csr_idx, csr_val, sidl, X2, w_gc3, b_gc3, gbuf);
    k_fc0    <<<(B * 512) / 256, 256, 0, stream>>>(x, w_fc0, b_fc0, hp0);
    k_bnstats<<<2, 256, 0, stream>>>(hp0, mu0, rstd0);
    k_fc1    <<<dim3(B, 4), 256, 0, stream>>>(hp0, mu0, rstd0, g_fc0, be_fc0, gbuf, w_fc1, b_fc1, hp1);
    k_bnstats<<<2, 256, 0, stream>>>(hp1, mu1, rstd1);
    k_out    <<<B, 64, 0, stream>>>(hp1, mu1, rstd1, g_fc1, be_fc1, w_fc2, b_fc2, (float*)d_out);
}